// Round 17
// baseline (1947.663 us; speedup 1.0000x reference)
//
#include <hip/hip_runtime.h>

typedef __bf16 bf16x8 __attribute__((ext_vector_type(8)));
typedef float  f32x4  __attribute__((ext_vector_type(4)));
typedef unsigned short u16;
typedef u16 u16x8 __attribute__((ext_vector_type(8)));
typedef u16 u16x4 __attribute__((ext_vector_type(4)));

__device__ __forceinline__ float bf2f(u16 h) {
  union { unsigned u; float f; } w; w.u = ((unsigned)h) << 16; return w.f;
}
__device__ __forceinline__ u16 f2bf(float f) {
  union { float f; unsigned u; } w; w.f = f;
  return (u16)((w.u + 0x7fffu + ((w.u >> 16) & 1u)) >> 16);
}

// ------- f32 -> bf16 weight conversion, all 5 tensors in one launch -------
__global__ __launch_bounds__(256)
void cvt_all(const float* __restrict__ s0, const float* __restrict__ s1,
             const float* __restrict__ s2, const float* __restrict__ s3,
             const float* __restrict__ s4, u16* __restrict__ dst) {
  long i = (long)blockIdx.x * 256 + threadIdx.x;
  float v;
  if (i < 1572864)      v = s0[i];
  else if (i < 2097152) v = s1[i - 1572864];
  else if (i < 4194304) v = s2[i - 2097152];
  else if (i < 6291456) v = s3[i - 4194304];
  else                  v = s4[i - 6291456];
  dst[i] = f2bf(v);
}

// ---- embedding + positional encoding: block per spatial pos, loop batch ----
__global__ __launch_bounds__(256)
void embed_kernel(const int* __restrict__ grd, const float* __restrict__ gold,
                  const float* __restrict__ emb, u16* __restrict__ xbf) {
  int p = blockIdx.x, c = threadIdx.x;           // p = y*64+x
  int y = p >> 6, xw = p & 63;
  int j = c & 63;
  float dv = expf(-(float)(2 * j) * (9.210340371976184f / 128.0f));
  float arg = ((c < 128) ? (float)xw : (float)y) * dv;
  float pos = (c & 64) ? cosf(arg) : sinf(arg);
  for (int b = 0; b < 16; ++b) {
    int t = b * 4096 + p;
    int g = grd[t];
    float v = (c < 254) ? emb[g * 254 + c] : gold[b * 2 + (c - 254)];
    xbf[(long)t * 256 + c] = f2bf(v + pos);
  }
}

// ============ gemm_qn: A staged ONCE, loop over all N tiles ============
template<int RELU, int ROWS>
__global__ __launch_bounds__(256)
void gemm_qn(const u16* __restrict__ A, const u16* __restrict__ W,
             const float* __restrict__ bias, u16* __restrict__ out,
             int Nout, int NT) {
  constexpr int NI = ROWS / 32;
  __shared__ u16 sA[ROWS * 256];
  __shared__ u16 sW[128 * 64];
  int tid = threadIdx.x;
  int lane = tid & 63, wave = tid >> 6;
  int wr = wave >> 1, wc = wave & 1;
  long rowbase = (long)blockIdx.x * ROWS;
  unsigned lbase = (unsigned)(tid & ~63) * 16;

  {
    int ac = tid & 31;
#pragma unroll
    for (int p = 0; p < ROWS / 8; ++p) {
      int row = p * 8 + (tid >> 5);
      int sc = (ac & 24) | ((ac ^ row) & 7);
      const u16* src = A + (rowbase + row) * 256 + sc * 8;
      __builtin_amdgcn_global_load_lds(
          (const __attribute__((address_space(1))) void*)src,
          (__attribute__((address_space(3))) void*)((char*)sA + p * 4096 + lbase),
          16, 0, 0);
    }
  }

  f32x4 acc[NI][4] = {};
  int T = NT * 4;
  for (int t = 0; t < T; ++t) {
    int nt = t >> 2, kc = t & 3;
    __syncthreads();
#pragma unroll
    for (int p = 0; p < 4; ++p) {
      int row = p * 32 + (tid >> 3);
      int sc = ((tid & 7) ^ row) & 7;
      const u16* src = W + (long)(nt * 128 + row) * 256 + kc * 64 + sc * 8;
      __builtin_amdgcn_global_load_lds(
          (const __attribute__((address_space(1))) void*)src,
          (__attribute__((address_space(3))) void*)((char*)sW + p * 4096 + lbase),
          16, 0, 0);
    }
    __syncthreads();

#pragma unroll
    for (int kk = 0; kk < 2; ++kk) {
      bf16x8 af[NI], bw[4];
#pragma unroll
      for (int i = 0; i < NI; ++i) {
        int ra = wr * (ROWS / 2) + i * 16 + (lane & 15);
        int l = kc * 8 + kk * 4 + (lane >> 4);
        int phys = (l & 24) | ((l ^ ra) & 7);
        af[i] = *(const bf16x8*)((const char*)sA + ra * 512 + phys * 16);
      }
#pragma unroll
      for (int j = 0; j < 4; ++j) {
        int rb = wc * 64 + j * 16 + (lane & 15);
        int m = kk * 4 + (lane >> 4);
        int phys = (m ^ rb) & 7;
        bw[j] = *(const bf16x8*)((const char*)sW + rb * 128 + phys * 16);
      }
#pragma unroll
      for (int i = 0; i < NI; ++i)
#pragma unroll
        for (int j = 0; j < 4; ++j)
          acc[i][j] = __builtin_amdgcn_mfma_f32_16x16x32_bf16(af[i], bw[j], acc[i][j], 0, 0, 0);
    }

    if (kc == 3) {
#pragma unroll
      for (int i = 0; i < NI; ++i) {
        long r0 = rowbase + wr * (ROWS / 2) + i * 16 + ((lane >> 4) * 4);
#pragma unroll
        for (int j = 0; j < 4; ++j) {
          long col = (long)nt * 128 + wc * 64 + j * 16 + (lane & 15);
          float bv = bias[col];
#pragma unroll
          for (int r = 0; r < 4; ++r) {
            float v = acc[i][j][r] + bv;
            if (RELU) v = fmaxf(v, 0.0f);
            out[(r0 + r) * Nout + col] = f2bf(v);
            acc[i][j][r] = 0.0f;
          }
        }
      }
    }
  }
}

// ====== gemm_pol: pol1 GEMM (N=512, ReLU) + pol2 (3x512 dot) fused ======
__global__ __launch_bounds__(256)
void gemm_pol(const u16* __restrict__ A, const u16* __restrict__ W,
              const float* __restrict__ b1, const float* __restrict__ pw2,
              const float* __restrict__ pb2, float* __restrict__ out) {
  __shared__ u16 sA[64 * 256];     // 32 KB
  __shared__ u16 sW[128 * 64];     // 16 KB
  __shared__ float part[2][3][64]; // 1.5 KB
  int tid = threadIdx.x;
  int lane = tid & 63, wave = tid >> 6;
  int wr = wave >> 1, wc = wave & 1;
  long rowbase = (long)blockIdx.x * 64;
  unsigned lbase = (unsigned)(tid & ~63) * 16;

  for (int i = tid; i < 384; i += 256) ((float*)part)[i] = 0.0f;

  {
    int ac = tid & 31;
#pragma unroll
    for (int p = 0; p < 8; ++p) {
      int row = p * 8 + (tid >> 5);
      int sc = (ac & 24) | ((ac ^ row) & 7);
      const u16* src = A + (rowbase + row) * 256 + sc * 8;
      __builtin_amdgcn_global_load_lds(
          (const __attribute__((address_space(1))) void*)src,
          (__attribute__((address_space(3))) void*)((char*)sA + p * 4096 + lbase),
          16, 0, 0);
    }
  }

  f32x4 acc[2][4] = {};
  for (int t = 0; t < 16; ++t) {          // NT=4 tiles x 4 k-chunks
    int nt = t >> 2, kc = t & 3;
    __syncthreads();
#pragma unroll
    for (int p = 0; p < 4; ++p) {
      int row = p * 32 + (tid >> 3);
      int sc = ((tid & 7) ^ row) & 7;
      const u16* src = W + (long)(nt * 128 + row) * 256 + kc * 64 + sc * 8;
      __builtin_amdgcn_global_load_lds(
          (const __attribute__((address_space(1))) void*)src,
          (__attribute__((address_space(3))) void*)((char*)sW + p * 4096 + lbase),
          16, 0, 0);
    }
    __syncthreads();

#pragma unroll
    for (int kk = 0; kk < 2; ++kk) {
      bf16x8 af[2], bw[4];
#pragma unroll
      for (int i = 0; i < 2; ++i) {
        int ra = wr * 32 + i * 16 + (lane & 15);
        int l = kc * 8 + kk * 4 + (lane >> 4);
        int phys = (l & 24) | ((l ^ ra) & 7);
        af[i] = *(const bf16x8*)((const char*)sA + ra * 512 + phys * 16);
      }
#pragma unroll
      for (int j = 0; j < 4; ++j) {
        int rb = wc * 64 + j * 16 + (lane & 15);
        int m = kk * 4 + (lane >> 4);
        int phys = (m ^ rb) & 7;
        bw[j] = *(const bf16x8*)((const char*)sW + rb * 128 + phys * 16);
      }
#pragma unroll
      for (int i = 0; i < 2; ++i)
#pragma unroll
        for (int j = 0; j < 4; ++j)
          acc[i][j] = __builtin_amdgcn_mfma_f32_16x16x32_bf16(af[i], bw[j], acc[i][j], 0, 0, 0);
    }

    if (kc == 3) {  // epilogue: h = relu(acc+b1); accumulate pol2 partials
#pragma unroll
      for (int i = 0; i < 2; ++i) {
#pragma unroll
        for (int r = 0; r < 4; ++r) {
          float p0 = 0.f, p1 = 0.f, p2 = 0.f;
#pragma unroll
          for (int j = 0; j < 4; ++j) {
            int col = nt * 128 + wc * 64 + j * 16 + (lane & 15);
            float v = fmaxf(acc[i][j][r] + b1[col], 0.0f);
            p0 += v * pw2[col];
            p1 += v * pw2[512 + col];
            p2 += v * pw2[1024 + col];
            acc[i][j][r] = 0.0f;
          }
#pragma unroll
          for (int m = 1; m < 16; m <<= 1) {
            p0 += __shfl_xor(p0, m); p1 += __shfl_xor(p1, m); p2 += __shfl_xor(p2, m);
          }
          if ((lane & 15) == 0) {
            int row = wr * 32 + i * 16 + (lane >> 4) * 4 + r;
            part[wc][0][row] += p0;
            part[wc][1][row] += p1;
            part[wc][2][row] += p2;
          }
        }
      }
    }
  }

  __syncthreads();
  if (tid < 64) {
    long t = rowbase + tid;
    float a0 = part[0][0][tid] + part[1][0][tid];
    float a1 = part[0][1][tid] + part[1][1][tid];
    float a2 = part[0][2][tid] + part[1][2][tid];
    out[t]          = a2 + pb2[2];
    out[65536 + t]  = a0 + pb2[0];
    out[131072 + t] = a1 + pb2[1];
  }
}

// ====== gemm_rln: GEMM(N=256) + bias + bf16 residual + LayerNorm fused ======
// 2-phase pipelined at BK=32: sA[2] 2x4K + sW[2] 2x16K = 40 KB (4 blocks/CU
// preserved). Per iter: stage(t+1) issued BEFORE compute(t); single barrier.
// Barrier count unchanged vs BK=64 1-phase; loads now overlap compute.
// Swizzle: 4 slots, phys = (chunk ^ (row>>1)) & 3, both sides (src + read).
template<int KC>
__global__ __launch_bounds__(256)
void gemm_rln(const u16* __restrict__ A, int lda, const u16* __restrict__ W,
              const float* __restrict__ bias, u16* __restrict__ xbf,
              const float* __restrict__ g, const float* __restrict__ b) {
  __shared__ __align__(16) char smem[40960];  // sA[2]:0,4096 | sW[2]:8192,24576
  float* red = (float*)smem;                   // LN scratch overlays sA
  int tid = threadIdx.x;
  int lane = tid & 63, wave = tid >> 6;
  int kg = lane >> 4;
  long rowbase = (long)blockIdx.x * 64;
  const int KW = KC * 64;

  auto stage = [&](int t, int buf) {
    {  // A chunk [64][32]: 1 pass
      int row = tid >> 2, c = tid & 3;
      int sc = (c ^ (row >> 1)) & 3;
      const u16* src = A + (rowbase + row) * lda + t * 32 + sc * 8;
      __builtin_amdgcn_global_load_lds(
          (const __attribute__((address_space(1))) void*)src,
          (__attribute__((address_space(3))) void*)(smem + buf * 4096 + tid * 16),
          16, 0, 0);
    }
#pragma unroll
    for (int p = 0; p < 4; ++p) {  // W chunk [256][32]: 4 passes
      int row = p * 64 + (tid >> 2), c = tid & 3;
      int sc = (c ^ (row >> 1)) & 3;
      const u16* src = W + (long)row * KW + t * 32 + sc * 8;
      __builtin_amdgcn_global_load_lds(
          (const __attribute__((address_space(1))) void*)src,
          (__attribute__((address_space(3))) void*)(smem + 8192 + buf * 16384 + p * 4096 + tid * 16),
          16, 0, 0);
    }
  };

  stage(0, 0);
  __syncthreads();   // drain prologue stage

  f32x4 acc[4][4] = {};
  const int NTI = KC * 2;
  for (int t = 0; t < NTI; ++t) {
    int cur = t & 1;
    if (t + 1 < NTI) stage(t + 1, cur ^ 1);   // prefetch overlaps compute
    bf16x8 af[4], bw[4];
#pragma unroll
    for (int i = 0; i < 4; ++i) {
      int ra = i * 16 + (lane & 15);
      int phys = (kg ^ (ra >> 1)) & 3;
      af[i] = *(const bf16x8*)(smem + cur * 4096 + ra * 64 + phys * 16);
    }
#pragma unroll
    for (int j = 0; j < 4; ++j) {
      int rb = wave * 64 + j * 16 + (lane & 15);
      int phys = (kg ^ (rb >> 1)) & 3;
      bw[j] = *(const bf16x8*)(smem + 8192 + cur * 16384 + rb * 64 + phys * 16);
    }
#pragma unroll
    for (int i = 0; i < 4; ++i)
#pragma unroll
      for (int j = 0; j < 4; ++j)
        acc[i][j] = __builtin_amdgcn_mfma_f32_16x16x32_bf16(af[i], bw[j], acc[i][j], 0, 0, 0);
    __syncthreads();   // drains prefetch; next iter's buffers ready
  }

  // ---- epilogue: v = acc + bias + bf16 residual; row stats; LN; store ----
  float gcol[4], bcol[4];
  long colb = wave * 64 + (lane & 15);
#pragma unroll
  for (int j = 0; j < 4; ++j) { gcol[j] = g[colb + j * 16]; bcol[j] = b[colb + j * 16]; }

#pragma unroll
  for (int i = 0; i < 4; ++i) {
#pragma unroll
    for (int r = 0; r < 4; ++r) {
      int rowl = i * 16 + (lane >> 4) * 4 + r;
      long rbase = (rowbase + rowl) * 256;
      float ps = 0.f, pss = 0.f;
#pragma unroll
      for (int j = 0; j < 4; ++j) {
        float v = acc[i][j][r] + bias[colb + j * 16] + bf2f(xbf[rbase + colb + j * 16]);
        acc[i][j][r] = v;
        ps += v; pss += v * v;
      }
#pragma unroll
      for (int m = 1; m < 16; m <<= 1) { ps += __shfl_xor(ps, m); pss += __shfl_xor(pss, m); }
      if ((lane & 15) == 0) {
        red[wave * 64 + rowl] = ps;
        red[256 + wave * 64 + rowl] = pss;
      }
    }
  }
  __syncthreads();
  if (tid < 64) {
    float s = red[tid] + red[64 + tid] + red[128 + tid] + red[192 + tid];
    float ss = red[256 + tid] + red[320 + tid] + red[384 + tid] + red[448 + tid];
    float mean = s * (1.0f / 256.0f);
    float var = ss * (1.0f / 256.0f) - mean * mean;
    red[512 + tid * 2] = mean;
    red[512 + tid * 2 + 1] = rsqrtf(var + 1e-5f);
  }
  __syncthreads();

#pragma unroll
  for (int i = 0; i < 4; ++i) {
#pragma unroll
    for (int r = 0; r < 4; ++r) {
      int rowl = i * 16 + (lane >> 4) * 4 + r;
      float mean = red[512 + rowl * 2];
      float rstd = red[512 + rowl * 2 + 1];
      long rbase = (rowbase + rowl) * 256;
#pragma unroll
      for (int j = 0; j < 4; ++j) {
        float o = (acc[i][j][r] - mean) * rstd * gcol[j] + bcol[j];
        xbf[rbase + colb + j * 16] = f2bf(o);
      }
    }
  }
}

// ------- hex attention: lane per (token, head-HALF) — 16 channels/lane -------
__global__ __launch_bounds__(256)
void attn_kernel(u16* __restrict__ qkv, const float* __restrict__ bin) {
  const int drA[7] = {0, 0, 0, 1, -1, -1, 1};
  const int dqA[7] = {0, 1, -1, 0, 0, 1, -1};
  int bid = blockIdx.x;
  int bswz = (bid & 7) * 512 + (bid >> 3);   // XCD-chunked, bijective (4096 = 8*512)
  int gid = bswz * 256 + threadIdx.x;
  int t = gid >> 4;
  int sub = gid & 15;
  int hoff = sub * 16;
  int b = t >> 12, y = (t >> 6) & 63, xw = t & 63;
  long tbase = (long)t * 768 + hoff;

  long tn[7]; float okf[7];
#pragma unroll
  for (int n = 0; n < 7; ++n) {
    int yy = y + drA[n], xx = xw + dqA[n];
    bool ok = ((unsigned)yy < 64u) && ((unsigned)xx < 64u);
    int yc = yy < 0 ? 0 : (yy > 63 ? 63 : yy);
    int xc = xx < 0 ? 0 : (xx > 63 ? 63 : xx);
    tn[n] = ((long)(b * 4096 + yc * 64 + xc)) * 768 + hoff;
    okf[n] = ok ? 1.0f : 0.0f;
  }

  u16x8 qraw[2], kr[7][2];
  {
    const u16x8* qp = (const u16x8*)(qkv + tbase);
    qraw[0] = qp[0]; qraw[1] = qp[1];
  }
#pragma unroll
  for (int n = 0; n < 7; ++n) {
    const u16x8* kp = (const u16x8*)(qkv + tn[n] + 256);
    kr[n][0] = kp[0]; kr[n][1] = kp[1];
  }

  float q[16];
#pragma unroll
  for (int j = 0; j < 2; ++j)
#pragma unroll
    for (int e = 0; e < 8; ++e) q[j * 8 + e] = bf2f(qraw[j][e]);

  float skb = 0.f;
  {
    const float* kb = bin + 256 + hoff;
#pragma unroll
    for (int i = 0; i < 16; ++i) skb += q[i] * kb[i];
  }

  float s[7];
#pragma unroll
  for (int n = 0; n < 7; ++n) {
    float acc = 0.f;
#pragma unroll
    for (int j = 0; j < 2; ++j)
#pragma unroll
      for (int e = 0; e < 8; ++e) acc += q[j * 8 + e] * bf2f(kr[n][j][e]);
    float p = (okf[n] != 0.f) ? acc : skb;
    p += __shfl_xor(p, 1);
    s[n] = p * 0.17677669529663687f;
  }

  u16x8 vr[7][2];
#pragma unroll
  for (int n = 0; n < 7; ++n) {
    const u16x8* vp = (const u16x8*)(qkv + tn[n] + 512);
    vr[n][0] = vp[0]; vr[n][1] = vp[1];
  }

  float mx = s[0];
#pragma unroll
  for (int n = 1; n < 7; ++n) mx = fmaxf(mx, s[n]);
  float wsum = 0.0f;
#pragma unroll
  for (int n = 0; n < 7; ++n) { s[n] = expf(s[n] - mx); wsum += s[n]; }
  float inv = 1.0f / wsum;

  float o[16];
#pragma unroll
  for (int i = 0; i < 16; ++i) o[i] = 0.0f;
  float woob = 0.f;
#pragma unroll
  for (int n = 0; n < 7; ++n) {
    float wk = okf[n] * s[n];
    woob += s[n] - wk;
#pragma unroll
    for (int j = 0; j < 2; ++j)
#pragma unroll
      for (int e = 0; e < 8; ++e) o[j * 8 + e] += wk * bf2f(vr[n][j][e]);
  }
  {
    const float* vb = bin + 512 + hoff;
#pragma unroll
    for (int i = 0; i < 16; ++i) o[i] += woob * vb[i];
  }

  u16x8* op = (u16x8*)(qkv + tbase);
#pragma unroll
  for (int j = 0; j < 2; ++j) {
    u16x8 ov;
#pragma unroll
    for (int e = 0; e < 8; ++e) ov[e] = f2bf(o[j * 8 + e] * inv);
    op[j] = ov;
  }
}

// ---------------- in-place final LayerNorm on xbf (wave per token) ----------------
__global__ __launch_bounds__(256)
void ln_kernel(u16* __restrict__ xbf, const float* __restrict__ g,
               const float* __restrict__ b) {
  int wave = threadIdx.x >> 6, lane = threadIdx.x & 63;
  long t = (long)blockIdx.x * 4 + wave;
  long base = t * 256 + lane * 4;
  u16x4 raw = *(const u16x4*)(xbf + base);
  float v0 = bf2f(raw[0]), v1 = bf2f(raw[1]), v2 = bf2f(raw[2]), v3 = bf2f(raw[3]);
  float s = v0 + v1 + v2 + v3;
  float ss = v0 * v0 + v1 * v1 + v2 * v2 + v3 * v3;
#pragma unroll
  for (int m = 1; m < 64; m <<= 1) { s += __shfl_xor(s, m); ss += __shfl_xor(ss, m); }
  float mean = s * (1.0f / 256.0f);
  float var = ss * (1.0f / 256.0f) - mean * mean;
  float rstd = rsqrtf(var + 1e-5f);
  float4 gv = *(const float4*)(g + lane * 4);
  float4 bv = *(const float4*)(b + lane * 4);
  u16x4 ob;
  ob[0] = f2bf((v0 - mean) * rstd * gv.x + bv.x);
  ob[1] = f2bf((v1 - mean) * rstd * gv.y + bv.y);
  ob[2] = f2bf((v2 - mean) * rstd * gv.z + bv.z);
  ob[3] = f2bf((v3 - mean) * rstd * gv.w + bv.w);
  *(u16x4*)(xbf + base) = ob;
}

// ---------------- spatial mean pooling stage 1 (reads bf16) ----------------
__global__ __launch_bounds__(256)
void pool1_kernel(const u16* __restrict__ xbf, float* __restrict__ part) {
  int bid = blockIdx.x, c = threadIdx.x;
  long base = (long)bid * 128 * 256;
  float s = 0.f;
  for (int p = 0; p < 128; ++p) s += bf2f(xbf[base + (long)p * 256 + c]);
  part[(long)bid * 256 + c] = s;
}

// ---------------- pool stage 2 + value head fused: one block per batch ----------------
__global__ __launch_bounds__(256)
void value_kernel(const float* __restrict__ part, const float* __restrict__ cw1,
                  const float* __restrict__ cb1, const float* __restrict__ cw2,
                  const float* __restrict__ cb2, float* __restrict__ out) {
  __shared__ float pooled[256];
  __shared__ float red[2];
  int b = blockIdx.x, c = threadIdx.x;
  float s = 0.f;
  for (int seg = 0; seg < 32; ++seg) s += part[((long)b * 32 + seg) * 256 + c];
  pooled[c] = s * (1.0f / 4096.0f);
  __syncthreads();
  if (c < 128) {
    float hj = cb1[c];
    const float* wr = cw1 + c * 256;
    for (int k = 0; k < 256; ++k) hj += pooled[k] * wr[k];
    hj = fmaxf(hj, 0.0f);
    float acc = hj * cw2[c];
#pragma unroll
    for (int m = 1; m < 64; m <<= 1) acc += __shfl_xor(acc, m);
    if ((c & 63) == 0) red[c >> 6] = acc;
  }
  __syncthreads();
  if (c == 0) out[196608 + b] = red[0] + red[1] + cb2[0];
}

extern "C" void kernel_launch(void* const* d_in, const int* in_sizes, int n_in,
                              void* d_out, int out_size, void* d_ws, size_t ws_size,
                              hipStream_t stream) {
  const int*   grd  = (const int*)d_in[0];
  const float* gold = (const float*)d_in[1];
  const float* emb  = (const float*)d_in[2];
  const float* in_w = (const float*)d_in[3];
  const float* in_b = (const float*)d_in[4];
  const float* out_w= (const float*)d_in[5];
  const float* out_b= (const float*)d_in[6];
  const float* l1_w = (const float*)d_in[7];
  const float* l1_b = (const float*)d_in[8];
  const float* l2_w = (const float*)d_in[9];
  const float* l2_b = (const float*)d_in[10];
  const float* n1_g = (const float*)d_in[11];
  const float* n1_b = (const float*)d_in[12];
  const float* n2_g = (const float*)d_in[13];
  const float* n2_b = (const float*)d_in[14];
  const float* fn_g = (const float*)d_in[15];
  const float* fn_b = (const float*)d_in[16];
  const float* pw1  = (const float*)d_in[17];
  const float* pb1  = (const float*)d_in[18];
  const float* pw2  = (const float*)d_in[19];
  const float* pb2  = (const float*)d_in[20];
  const float* cw1  = (const float*)d_in[21];
  const float* cb1  = (const float*)d_in[22];
  const float* cw2  = (const float*)d_in[23];
  const float* cb2  = (const float*)d_in[24];
  float* out = (float*)d_out;

  // ---- workspace layout: peak ~175 MB ----
  char* ws = (char*)d_ws;
  u16*   xbf    = (u16*)ws;                            //   0..32 MB  bf16 residual stream
  char*  region = ws + (32l << 20);                    //  32..160 MB shared
  u16*   qkv    = (u16*)region;                        //   qkv [N,768] bf16 (96 MB)
  u16*   hbuf   = (u16*)region;                        //   ffn hidden full [N,1024] (128 MB)
  u16*   wbf    = (u16*)(ws + (160l << 20));           // 160..172.3 MB bf16 weights
  float* part   = (float*)(ws + (173l << 20));         // 173 MB +512 KB

  u16* inw_bf  = wbf;
  u16* outw_bf = inw_bf + 1572864;
  u16* l1w_bf  = outw_bf + 524288;
  u16* l2w_bf  = l1w_bf + 2097152;
  u16* pw1_bf  = l2w_bf + 2097152;

  // all 5 weight conversions in one launch (wbf is contiguous in this order)
  cvt_all<<<25088, 256, 0, stream>>>(in_w, out_w, l1_w, l2_w, pw1, wbf);

  // embedding + posenc: block per spatial position, batch loop inside
  embed_kernel<<<4096, 256, 0, stream>>>(grd, gold, emb, xbf);

  for (int i = 0; i < 8; ++i) {
    // QKV projection: 128-row blocks (A staged once wins here), 6 N-tiles
    gemm_qn<0, 128><<<512, 256, 0, stream>>>(
        xbf, inw_bf + (long)i * 196608, in_b + i * 768, qkv, 768, 6);
    // hex attention, half-head per lane, in place into q-slice
    attn_kernel<<<4096, 256, 0, stream>>>(qkv, in_b + i * 768);
    // out-projection + bf16 residual + LN1 (2-phase pipelined)
    gemm_rln<4><<<1024, 256, 0, stream>>>(
        qkv, 768, outw_bf + (long)i * 65536, out_b + i * 256, xbf,
        n1_g + i * 256, n1_b + i * 256);
    // FFN over full N (hbuf 128 MB aliases dead qkv)
    gemm_qn<1, 128><<<512, 256, 0, stream>>>(
        xbf, l1w_bf + (long)i * 262144, l1_b + i * 1024, hbuf, 1024, 8);
    gemm_rln<16><<<1024, 256, 0, stream>>>(
        hbuf, 1024, l2w_bf + (long)i * 262144, l2_b + i * 256, xbf,
        n2_g + i * 256, n2_b + i * 256);
  }

  ln_kernel<<<16384, 256, 0, stream>>>(xbf, fn_g, fn_b);

  // policy head: pol1 GEMM + pol2 fused, no hidden materialization
  gemm_pol<<<1024, 256, 0, stream>>>(xbf, pw1_bf, pb1, pw2, pb2, out);

  // value head: pool1 then fused pool2+value
  pool1_kernel<<<512, 256, 0, stream>>>(xbf, part);
  value_kernel<<<16, 256, 0, stream>>>(part, cw1, cb1, cw2, cb2, out);
}

// Round 18
// 1905.956 us; speedup vs baseline: 1.0219x; 1.0219x over previous
//
#include <hip/hip_runtime.h>

typedef __bf16 bf16x8 __attribute__((ext_vector_type(8)));
typedef float  f32x4  __attribute__((ext_vector_type(4)));
typedef unsigned short u16;
typedef u16 u16x8 __attribute__((ext_vector_type(8)));
typedef u16 u16x4 __attribute__((ext_vector_type(4)));

__device__ __forceinline__ float bf2f(u16 h) {
  union { unsigned u; float f; } w; w.u = ((unsigned)h) << 16; return w.f;
}
__device__ __forceinline__ u16 f2bf(float f) {
  union { float f; unsigned u; } w; w.f = f;
  return (u16)((w.u + 0x7fffu + ((w.u >> 16) & 1u)) >> 16);
}

// ------- f32 -> bf16 weight conversion, all 5 tensors in one launch -------
// dst (wbf) is contiguous in order: in_w | out_w | l1_w | l2_w | pw1.
__global__ __launch_bounds__(256)
void cvt_all(const float* __restrict__ s0, const float* __restrict__ s1,
             const float* __restrict__ s2, const float* __restrict__ s3,
             const float* __restrict__ s4, u16* __restrict__ dst) {
  long i = (long)blockIdx.x * 256 + threadIdx.x;
  float v;
  if (i < 1572864)      v = s0[i];
  else if (i < 2097152) v = s1[i - 1572864];
  else if (i < 4194304) v = s2[i - 2097152];
  else if (i < 6291456) v = s3[i - 4194304];
  else                  v = s4[i - 6291456];
  dst[i] = f2bf(v);
}

// ---- embedding + positional encoding: block per spatial pos, loop batch ----
// Trig computed once per (pos, channel) instead of 16x; emb rows L2-reused.
__global__ __launch_bounds__(256)
void embed_kernel(const int* __restrict__ grd, const float* __restrict__ gold,
                  const float* __restrict__ emb, u16* __restrict__ xbf) {
  int p = blockIdx.x, c = threadIdx.x;           // p = y*64+x
  int y = p >> 6, xw = p & 63;
  int j = c & 63;
  float dv = expf(-(float)(2 * j) * (9.210340371976184f / 128.0f));
  float arg = ((c < 128) ? (float)xw : (float)y) * dv;
  float pos = (c & 64) ? cosf(arg) : sinf(arg);
  for (int b = 0; b < 16; ++b) {
    int t = b * 4096 + p;
    int g = grd[t];
    float v = (c < 254) ? emb[g * 254 + c] : gold[b * 2 + (c - 254)];
    xbf[(long)t * 256 + c] = f2bf(v + pos);
  }
}

// ============ gemm_qn: A staged ONCE, loop over all N tiles ============
template<int RELU, int ROWS>
__global__ __launch_bounds__(256)
void gemm_qn(const u16* __restrict__ A, const u16* __restrict__ W,
             const float* __restrict__ bias, u16* __restrict__ out,
             int Nout, int NT) {
  constexpr int NI = ROWS / 32;
  __shared__ u16 sA[ROWS * 256];
  __shared__ u16 sW[128 * 64];
  int tid = threadIdx.x;
  int lane = tid & 63, wave = tid >> 6;
  int wr = wave >> 1, wc = wave & 1;
  long rowbase = (long)blockIdx.x * ROWS;
  unsigned lbase = (unsigned)(tid & ~63) * 16;

  {
    int ac = tid & 31;
#pragma unroll
    for (int p = 0; p < ROWS / 8; ++p) {
      int row = p * 8 + (tid >> 5);
      int sc = (ac & 24) | ((ac ^ row) & 7);
      const u16* src = A + (rowbase + row) * 256 + sc * 8;
      __builtin_amdgcn_global_load_lds(
          (const __attribute__((address_space(1))) void*)src,
          (__attribute__((address_space(3))) void*)((char*)sA + p * 4096 + lbase),
          16, 0, 0);
    }
  }

  f32x4 acc[NI][4] = {};
  int T = NT * 4;
  for (int t = 0; t < T; ++t) {
    int nt = t >> 2, kc = t & 3;
    __syncthreads();
#pragma unroll
    for (int p = 0; p < 4; ++p) {
      int row = p * 32 + (tid >> 3);
      int sc = ((tid & 7) ^ row) & 7;
      const u16* src = W + (long)(nt * 128 + row) * 256 + kc * 64 + sc * 8;
      __builtin_amdgcn_global_load_lds(
          (const __attribute__((address_space(1))) void*)src,
          (__attribute__((address_space(3))) void*)((char*)sW + p * 4096 + lbase),
          16, 0, 0);
    }
    __syncthreads();

#pragma unroll
    for (int kk = 0; kk < 2; ++kk) {
      bf16x8 af[NI], bw[4];
#pragma unroll
      for (int i = 0; i < NI; ++i) {
        int ra = wr * (ROWS / 2) + i * 16 + (lane & 15);
        int l = kc * 8 + kk * 4 + (lane >> 4);
        int phys = (l & 24) | ((l ^ ra) & 7);
        af[i] = *(const bf16x8*)((const char*)sA + ra * 512 + phys * 16);
      }
#pragma unroll
      for (int j = 0; j < 4; ++j) {
        int rb = wc * 64 + j * 16 + (lane & 15);
        int m = kk * 4 + (lane >> 4);
        int phys = (m ^ rb) & 7;
        bw[j] = *(const bf16x8*)((const char*)sW + rb * 128 + phys * 16);
      }
#pragma unroll
      for (int i = 0; i < NI; ++i)
#pragma unroll
        for (int j = 0; j < 4; ++j)
          acc[i][j] = __builtin_amdgcn_mfma_f32_16x16x32_bf16(af[i], bw[j], acc[i][j], 0, 0, 0);
    }

    if (kc == 3) {
#pragma unroll
      for (int i = 0; i < NI; ++i) {
        long r0 = rowbase + wr * (ROWS / 2) + i * 16 + ((lane >> 4) * 4);
#pragma unroll
        for (int j = 0; j < 4; ++j) {
          long col = (long)nt * 128 + wc * 64 + j * 16 + (lane & 15);
          float bv = bias[col];
#pragma unroll
          for (int r = 0; r < 4; ++r) {
            float v = acc[i][j][r] + bv;
            if (RELU) v = fmaxf(v, 0.0f);
            out[(r0 + r) * Nout + col] = f2bf(v);
            acc[i][j][r] = 0.0f;
          }
        }
      }
    }
  }
}

// ====== gemm_pol: pol1 GEMM (N=512, ReLU) + pol2 (3x512 dot) fused ======
__global__ __launch_bounds__(256)
void gemm_pol(const u16* __restrict__ A, const u16* __restrict__ W,
              const float* __restrict__ b1, const float* __restrict__ pw2,
              const float* __restrict__ pb2, float* __restrict__ out) {
  __shared__ u16 sA[64 * 256];     // 32 KB
  __shared__ u16 sW[128 * 64];     // 16 KB
  __shared__ float part[2][3][64]; // 1.5 KB
  int tid = threadIdx.x;
  int lane = tid & 63, wave = tid >> 6;
  int wr = wave >> 1, wc = wave & 1;
  long rowbase = (long)blockIdx.x * 64;
  unsigned lbase = (unsigned)(tid & ~63) * 16;

  for (int i = tid; i < 384; i += 256) ((float*)part)[i] = 0.0f;

  {
    int ac = tid & 31;
#pragma unroll
    for (int p = 0; p < 8; ++p) {
      int row = p * 8 + (tid >> 5);
      int sc = (ac & 24) | ((ac ^ row) & 7);
      const u16* src = A + (rowbase + row) * 256 + sc * 8;
      __builtin_amdgcn_global_load_lds(
          (const __attribute__((address_space(1))) void*)src,
          (__attribute__((address_space(3))) void*)((char*)sA + p * 4096 + lbase),
          16, 0, 0);
    }
  }

  f32x4 acc[2][4] = {};
  for (int t = 0; t < 16; ++t) {          // NT=4 tiles x 4 k-chunks
    int nt = t >> 2, kc = t & 3;
    __syncthreads();
#pragma unroll
    for (int p = 0; p < 4; ++p) {
      int row = p * 32 + (tid >> 3);
      int sc = ((tid & 7) ^ row) & 7;
      const u16* src = W + (long)(nt * 128 + row) * 256 + kc * 64 + sc * 8;
      __builtin_amdgcn_global_load_lds(
          (const __attribute__((address_space(1))) void*)src,
          (__attribute__((address_space(3))) void*)((char*)sW + p * 4096 + lbase),
          16, 0, 0);
    }
    __syncthreads();

#pragma unroll
    for (int kk = 0; kk < 2; ++kk) {
      bf16x8 af[2], bw[4];
#pragma unroll
      for (int i = 0; i < 2; ++i) {
        int ra = wr * 32 + i * 16 + (lane & 15);
        int l = kc * 8 + kk * 4 + (lane >> 4);
        int phys = (l & 24) | ((l ^ ra) & 7);
        af[i] = *(const bf16x8*)((const char*)sA + ra * 512 + phys * 16);
      }
#pragma unroll
      for (int j = 0; j < 4; ++j) {
        int rb = wc * 64 + j * 16 + (lane & 15);
        int m = kk * 4 + (lane >> 4);
        int phys = (m ^ rb) & 7;
        bw[j] = *(const bf16x8*)((const char*)sW + rb * 128 + phys * 16);
      }
#pragma unroll
      for (int i = 0; i < 2; ++i)
#pragma unroll
        for (int j = 0; j < 4; ++j)
          acc[i][j] = __builtin_amdgcn_mfma_f32_16x16x32_bf16(af[i], bw[j], acc[i][j], 0, 0, 0);
    }

    if (kc == 3) {  // epilogue: h = relu(acc+b1); accumulate pol2 partials
#pragma unroll
      for (int i = 0; i < 2; ++i) {
#pragma unroll
        for (int r = 0; r < 4; ++r) {
          float p0 = 0.f, p1 = 0.f, p2 = 0.f;
#pragma unroll
          for (int j = 0; j < 4; ++j) {
            int col = nt * 128 + wc * 64 + j * 16 + (lane & 15);
            float v = fmaxf(acc[i][j][r] + b1[col], 0.0f);
            p0 += v * pw2[col];
            p1 += v * pw2[512 + col];
            p2 += v * pw2[1024 + col];
            acc[i][j][r] = 0.0f;
          }
#pragma unroll
          for (int m = 1; m < 16; m <<= 1) {
            p0 += __shfl_xor(p0, m); p1 += __shfl_xor(p1, m); p2 += __shfl_xor(p2, m);
          }
          if ((lane & 15) == 0) {
            int row = wr * 32 + i * 16 + (lane >> 4) * 4 + r;
            part[wc][0][row] += p0;
            part[wc][1][row] += p1;
            part[wc][2][row] += p2;
          }
        }
      }
    }
  }

  __syncthreads();
  if (tid < 64) {
    long t = rowbase + tid;
    float a0 = part[0][0][tid] + part[1][0][tid];
    float a1 = part[0][1][tid] + part[1][1][tid];
    float a2 = part[0][2][tid] + part[1][2][tid];
    out[t]          = a2 + pb2[2];
    out[65536 + t]  = a0 + pb2[0];
    out[131072 + t] = a1 + pb2[1];
  }
}

// ====== gemm_rln: GEMM(N=256) + bias + bf16 residual + LayerNorm fused ======
// 64 rows/block, 256 threads, 40KB LDS -> 4 blocks/CU (grid 1024 = max MLP).
template<int KC>
__global__ __launch_bounds__(256)
void gemm_rln(const u16* __restrict__ A, int lda, const u16* __restrict__ W,
              const float* __restrict__ bias, u16* __restrict__ xbf,
              const float* __restrict__ g, const float* __restrict__ b) {
  __shared__ __align__(16) char smem[40960];  // sA 8K | sW 32K; red overlays sA
  u16* sAr = (u16*)smem;
  u16* sWr = (u16*)(smem + 8192);
  float* red = (float*)smem;
  int tid = threadIdx.x;
  int lane = tid & 63, wave = tid >> 6;
  long rowbase = (long)blockIdx.x * 64;
  unsigned lbase = (unsigned)(tid & ~63) * 16;

  f32x4 acc[4][4] = {};
  for (int kc = 0; kc < KC; ++kc) {
    __syncthreads();
#pragma unroll
    for (int p = 0; p < 2; ++p) {
      int row = p * 32 + (tid >> 3);
      int sc = ((tid & 7) ^ row) & 7;
      const u16* src = A + (rowbase + row) * lda + kc * 64 + sc * 8;
      __builtin_amdgcn_global_load_lds(
          (const __attribute__((address_space(1))) void*)src,
          (__attribute__((address_space(3))) void*)((char*)sAr + p * 4096 + lbase),
          16, 0, 0);
    }
#pragma unroll
    for (int p = 0; p < 8; ++p) {
      int row = p * 32 + (tid >> 3);
      int sc = ((tid & 7) ^ row) & 7;
      const u16* src = W + (long)row * (KC * 64) + kc * 64 + sc * 8;
      __builtin_amdgcn_global_load_lds(
          (const __attribute__((address_space(1))) void*)src,
          (__attribute__((address_space(3))) void*)((char*)sWr + p * 4096 + lbase),
          16, 0, 0);
    }
    __syncthreads();

#pragma unroll
    for (int kk = 0; kk < 2; ++kk) {
      bf16x8 af[4], bw[4];
#pragma unroll
      for (int i = 0; i < 4; ++i) {
        int ra = i * 16 + (lane & 15);
        int m = kk * 4 + (lane >> 4);
        int phys = (m ^ ra) & 7;
        af[i] = *(const bf16x8*)((const char*)sAr + ra * 128 + phys * 16);
      }
#pragma unroll
      for (int j = 0; j < 4; ++j) {
        int rb = wave * 64 + j * 16 + (lane & 15);
        int m = kk * 4 + (lane >> 4);
        int phys = (m ^ rb) & 7;
        bw[j] = *(const bf16x8*)((const char*)sWr + rb * 128 + phys * 16);
      }
#pragma unroll
      for (int i = 0; i < 4; ++i)
#pragma unroll
        for (int j = 0; j < 4; ++j)
          acc[i][j] = __builtin_amdgcn_mfma_f32_16x16x32_bf16(af[i], bw[j], acc[i][j], 0, 0, 0);
    }
  }

  float gcol[4], bcol[4];
  long colb = wave * 64 + (lane & 15);
#pragma unroll
  for (int j = 0; j < 4; ++j) { gcol[j] = g[colb + j * 16]; bcol[j] = b[colb + j * 16]; }

  __syncthreads();

#pragma unroll
  for (int i = 0; i < 4; ++i) {
#pragma unroll
    for (int r = 0; r < 4; ++r) {
      int rowl = i * 16 + (lane >> 4) * 4 + r;
      long rbase = (rowbase + rowl) * 256;
      float ps = 0.f, pss = 0.f;
#pragma unroll
      for (int j = 0; j < 4; ++j) {
        float v = acc[i][j][r] + bias[colb + j * 16] + bf2f(xbf[rbase + colb + j * 16]);
        acc[i][j][r] = v;
        ps += v; pss += v * v;
      }
#pragma unroll
      for (int m = 1; m < 16; m <<= 1) { ps += __shfl_xor(ps, m); pss += __shfl_xor(pss, m); }
      if ((lane & 15) == 0) {
        red[wave * 64 + rowl] = ps;
        red[256 + wave * 64 + rowl] = pss;
      }
    }
  }
  __syncthreads();
  if (tid < 64) {
    float s = red[tid] + red[64 + tid] + red[128 + tid] + red[192 + tid];
    float ss = red[256 + tid] + red[320 + tid] + red[384 + tid] + red[448 + tid];
    float mean = s * (1.0f / 256.0f);
    float var = ss * (1.0f / 256.0f) - mean * mean;
    red[512 + tid * 2] = mean;
    red[512 + tid * 2 + 1] = rsqrtf(var + 1e-5f);
  }
  __syncthreads();

#pragma unroll
  for (int i = 0; i < 4; ++i) {
#pragma unroll
    for (int r = 0; r < 4; ++r) {
      int rowl = i * 16 + (lane >> 4) * 4 + r;
      float mean = red[512 + rowl * 2];
      float rstd = red[512 + rowl * 2 + 1];
      long rbase = (rowbase + rowl) * 256;
#pragma unroll
      for (int j = 0; j < 4; ++j) {
        float o = (acc[i][j][r] - mean) * rstd * gcol[j] + bcol[j];
        xbf[rbase + colb + j * 16] = f2bf(o);
      }
    }
  }
}

// ------- hex attention: lane per (token, head-HALF) — 16 channels/lane -------
__global__ __launch_bounds__(256)
void attn_kernel(u16* __restrict__ qkv, const float* __restrict__ bin) {
  const int drA[7] = {0, 0, 0, 1, -1, -1, 1};
  const int dqA[7] = {0, 1, -1, 0, 0, 1, -1};
  int bid = blockIdx.x;
  int bswz = (bid & 7) * 512 + (bid >> 3);   // XCD-chunked, bijective (4096 = 8*512)
  int gid = bswz * 256 + threadIdx.x;
  int t = gid >> 4;
  int sub = gid & 15;
  int hoff = sub * 16;
  int b = t >> 12, y = (t >> 6) & 63, xw = t & 63;
  long tbase = (long)t * 768 + hoff;

  long tn[7]; float okf[7];
#pragma unroll
  for (int n = 0; n < 7; ++n) {
    int yy = y + drA[n], xx = xw + dqA[n];
    bool ok = ((unsigned)yy < 64u) && ((unsigned)xx < 64u);
    int yc = yy < 0 ? 0 : (yy > 63 ? 63 : yy);
    int xc = xx < 0 ? 0 : (xx > 63 ? 63 : xx);
    tn[n] = ((long)(b * 4096 + yc * 64 + xc)) * 768 + hoff;
    okf[n] = ok ? 1.0f : 0.0f;
  }

  u16x8 qraw[2], kr[7][2];
  {
    const u16x8* qp = (const u16x8*)(qkv + tbase);
    qraw[0] = qp[0]; qraw[1] = qp[1];
  }
#pragma unroll
  for (int n = 0; n < 7; ++n) {
    const u16x8* kp = (const u16x8*)(qkv + tn[n] + 256);
    kr[n][0] = kp[0]; kr[n][1] = kp[1];
  }

  float q[16];
#pragma unroll
  for (int j = 0; j < 2; ++j)
#pragma unroll
    for (int e = 0; e < 8; ++e) q[j * 8 + e] = bf2f(qraw[j][e]);

  float skb = 0.f;
  {
    const float* kb = bin + 256 + hoff;
#pragma unroll
    for (int i = 0; i < 16; ++i) skb += q[i] * kb[i];
  }

  float s[7];
#pragma unroll
  for (int n = 0; n < 7; ++n) {
    float acc = 0.f;
#pragma unroll
    for (int j = 0; j < 2; ++j)
#pragma unroll
      for (int e = 0; e < 8; ++e) acc += q[j * 8 + e] * bf2f(kr[n][j][e]);
    float p = (okf[n] != 0.f) ? acc : skb;
    p += __shfl_xor(p, 1);
    s[n] = p * 0.17677669529663687f;
  }

  u16x8 vr[7][2];
#pragma unroll
  for (int n = 0; n < 7; ++n) {
    const u16x8* vp = (const u16x8*)(qkv + tn[n] + 512);
    vr[n][0] = vp[0]; vr[n][1] = vp[1];
  }

  float mx = s[0];
#pragma unroll
  for (int n = 1; n < 7; ++n) mx = fmaxf(mx, s[n]);
  float wsum = 0.0f;
#pragma unroll
  for (int n = 0; n < 7; ++n) { s[n] = expf(s[n] - mx); wsum += s[n]; }
  float inv = 1.0f / wsum;

  float o[16];
#pragma unroll
  for (int i = 0; i < 16; ++i) o[i] = 0.0f;
  float woob = 0.f;
#pragma unroll
  for (int n = 0; n < 7; ++n) {
    float wk = okf[n] * s[n];
    woob += s[n] - wk;
#pragma unroll
    for (int j = 0; j < 2; ++j)
#pragma unroll
      for (int e = 0; e < 8; ++e) o[j * 8 + e] += wk * bf2f(vr[n][j][e]);
  }
  {
    const float* vb = bin + 512 + hoff;
#pragma unroll
    for (int i = 0; i < 16; ++i) o[i] += woob * vb[i];
  }

  u16x8* op = (u16x8*)(qkv + tbase);
#pragma unroll
  for (int j = 0; j < 2; ++j) {
    u16x8 ov;
#pragma unroll
    for (int e = 0; e < 8; ++e) ov[e] = f2bf(o[j * 8 + e] * inv);
    op[j] = ov;
  }
}

// ---------------- in-place final LayerNorm on xbf (wave per token) ----------------
__global__ __launch_bounds__(256)
void ln_kernel(u16* __restrict__ xbf, const float* __restrict__ g,
               const float* __restrict__ b) {
  int wave = threadIdx.x >> 6, lane = threadIdx.x & 63;
  long t = (long)blockIdx.x * 4 + wave;
  long base = t * 256 + lane * 4;
  u16x4 raw = *(const u16x4*)(xbf + base);
  float v0 = bf2f(raw[0]), v1 = bf2f(raw[1]), v2 = bf2f(raw[2]), v3 = bf2f(raw[3]);
  float s = v0 + v1 + v2 + v3;
  float ss = v0 * v0 + v1 * v1 + v2 * v2 + v3 * v3;
#pragma unroll
  for (int m = 1; m < 64; m <<= 1) { s += __shfl_xor(s, m); ss += __shfl_xor(ss, m); }
  float mean = s * (1.0f / 256.0f);
  float var = ss * (1.0f / 256.0f) - mean * mean;
  float rstd = rsqrtf(var + 1e-5f);
  float4 gv = *(const float4*)(g + lane * 4);
  float4 bv = *(const float4*)(b + lane * 4);
  u16x4 ob;
  ob[0] = f2bf((v0 - mean) * rstd * gv.x + bv.x);
  ob[1] = f2bf((v1 - mean) * rstd * gv.y + bv.y);
  ob[2] = f2bf((v2 - mean) * rstd * gv.z + bv.z);
  ob[3] = f2bf((v3 - mean) * rstd * gv.w + bv.w);
  *(u16x4*)(xbf + base) = ob;
}

// ---------------- spatial mean pooling stage 1 (reads bf16) ----------------
__global__ __launch_bounds__(256)
void pool1_kernel(const u16* __restrict__ xbf, float* __restrict__ part) {
  int bid = blockIdx.x, c = threadIdx.x;
  long base = (long)bid * 128 * 256;
  float s = 0.f;
  for (int p = 0; p < 128; ++p) s += bf2f(xbf[base + (long)p * 256 + c]);
  part[(long)bid * 256 + c] = s;
}

// ---------------- pool stage 2 + value head fused: one block per batch ----------------
__global__ __launch_bounds__(256)
void value_kernel(const float* __restrict__ part, const float* __restrict__ cw1,
                  const float* __restrict__ cb1, const float* __restrict__ cw2,
                  const float* __restrict__ cb2, float* __restrict__ out) {
  __shared__ float pooled[256];
  __shared__ float red[2];
  int b = blockIdx.x, c = threadIdx.x;
  float s = 0.f;
  for (int seg = 0; seg < 32; ++seg) s += part[((long)b * 32 + seg) * 256 + c];
  pooled[c] = s * (1.0f / 4096.0f);
  __syncthreads();
  if (c < 128) {
    float hj = cb1[c];
    const float* wr = cw1 + c * 256;
    for (int k = 0; k < 256; ++k) hj += pooled[k] * wr[k];
    hj = fmaxf(hj, 0.0f);
    float acc = hj * cw2[c];
#pragma unroll
    for (int m = 1; m < 64; m <<= 1) acc += __shfl_xor(acc, m);
    if ((c & 63) == 0) red[c >> 6] = acc;
  }
  __syncthreads();
  if (c == 0) out[196608 + b] = red[0] + red[1] + cb2[0];
}

extern "C" void kernel_launch(void* const* d_in, const int* in_sizes, int n_in,
                              void* d_out, int out_size, void* d_ws, size_t ws_size,
                              hipStream_t stream) {
  const int*   grd  = (const int*)d_in[0];
  const float* gold = (const float*)d_in[1];
  const float* emb  = (const float*)d_in[2];
  const float* in_w = (const float*)d_in[3];
  const float* in_b = (const float*)d_in[4];
  const float* out_w= (const float*)d_in[5];
  const float* out_b= (const float*)d_in[6];
  const float* l1_w = (const float*)d_in[7];
  const float* l1_b = (const float*)d_in[8];
  const float* l2_w = (const float*)d_in[9];
  const float* l2_b = (const float*)d_in[10];
  const float* n1_g = (const float*)d_in[11];
  const float* n1_b = (const float*)d_in[12];
  const float* n2_g = (const float*)d_in[13];
  const float* n2_b = (const float*)d_in[14];
  const float* fn_g = (const float*)d_in[15];
  const float* fn_b = (const float*)d_in[16];
  const float* pw1  = (const float*)d_in[17];
  const float* pb1  = (const float*)d_in[18];
  const float* pw2  = (const float*)d_in[19];
  const float* pb2  = (const float*)d_in[20];
  const float* cw1  = (const float*)d_in[21];
  const float* cb1  = (const float*)d_in[22];
  const float* cw2  = (const float*)d_in[23];
  const float* cb2  = (const float*)d_in[24];
  float* out = (float*)d_out;

  // ---- workspace layout: peak ~175 MB ----
  char* ws = (char*)d_ws;
  u16*   xbf    = (u16*)ws;                            //   0..32 MB  bf16 residual stream
  char*  region = ws + (32l << 20);                    //  32..160 MB shared
  u16*   qkv    = (u16*)region;                        //   qkv [N,768] bf16 (96 MB)
  u16*   hbuf   = (u16*)region;                        //   ffn hidden full [N,1024] (128 MB)
  u16*   wbf    = (u16*)(ws + (160l << 20));           // 160..172.3 MB bf16 weights
  float* part   = (float*)(ws + (173l << 20));         // 173 MB +512 KB

  u16* inw_bf  = wbf;
  u16* outw_bf = inw_bf + 1572864;
  u16* l1w_bf  = outw_bf + 524288;
  u16* l2w_bf  = l1w_bf + 2097152;
  u16* pw1_bf  = l2w_bf + 2097152;

  // all 5 weight conversions in one launch (wbf is contiguous in this order)
  cvt_all<<<25088, 256, 0, stream>>>(in_w, out_w, l1_w, l2_w, pw1, wbf);

  // embedding + posenc: block per spatial position, batch loop inside
  embed_kernel<<<4096, 256, 0, stream>>>(grd, gold, emb, xbf);

  for (int i = 0; i < 8; ++i) {
    // QKV projection: 128-row blocks (A staged once wins here), 6 N-tiles
    gemm_qn<0, 128><<<512, 256, 0, stream>>>(
        xbf, inw_bf + (long)i * 196608, in_b + i * 768, qkv, 768, 6);
    // hex attention, half-head per lane, in place into q-slice
    attn_kernel<<<4096, 256, 0, stream>>>(qkv, in_b + i * 768);
    // out-projection + bf16 residual + LN1 (64-row: 4 blocks/CU MLP wins here)
    gemm_rln<4><<<1024, 256, 0, stream>>>(
        qkv, 768, outw_bf + (long)i * 65536, out_b + i * 256, xbf,
        n1_g + i * 256, n1_b + i * 256);
    // FFN over full N (hbuf 128 MB aliases dead qkv)
    gemm_qn<1, 128><<<512, 256, 0, stream>>>(
        xbf, l1w_bf + (long)i * 262144, l1_b + i * 1024, hbuf, 1024, 8);
    gemm_rln<16><<<1024, 256, 0, stream>>>(
        hbuf, 1024, l2w_bf + (long)i * 262144, l2_b + i * 256, xbf,
        n2_g + i * 256, n2_b + i * 256);
  }

  ln_kernel<<<16384, 256, 0, stream>>>(xbf, fn_g, fn_b);

  // policy head: pol1 GEMM + pol2 fused, no hidden materialization
  gemm_pol<<<1024, 256, 0, stream>>>(xbf, pw1_bf, pb1, pw2, pb2, out);

  // value head: pool1 then fused pool2+value
  pool1_kernel<<<512, 256, 0, stream>>>(xbf, part);
  value_kernel<<<16, 256, 0, stream>>>(part, cw1, cb1, cw2, cb2, out);
}

// Round 19
// 1903.522 us; speedup vs baseline: 1.0232x; 1.0013x over previous
//
#include <hip/hip_runtime.h>

typedef __bf16 bf16x8 __attribute__((ext_vector_type(8)));
typedef float  f32x4  __attribute__((ext_vector_type(4)));
typedef unsigned short u16;
typedef u16 u16x8 __attribute__((ext_vector_type(8)));
typedef u16 u16x4 __attribute__((ext_vector_type(4)));

__device__ __forceinline__ float bf2f(u16 h) {
  union { unsigned u; float f; } w; w.u = ((unsigned)h) << 16; return w.f;
}
__device__ __forceinline__ u16 f2bf(float f) {
  union { float f; unsigned u; } w; w.f = f;
  return (u16)((w.u + 0x7fffu + ((w.u >> 16) & 1u)) >> 16);
}

// ------- f32 -> bf16 weight conversion, all 5 tensors in one launch -------
__global__ __launch_bounds__(256)
void cvt_all(const float* __restrict__ s0, const float* __restrict__ s1,
             const float* __restrict__ s2, const float* __restrict__ s3,
             const float* __restrict__ s4, u16* __restrict__ dst) {
  long i = (long)blockIdx.x * 256 + threadIdx.x;
  float v;
  if (i < 1572864)      v = s0[i];
  else if (i < 2097152) v = s1[i - 1572864];
  else if (i < 4194304) v = s2[i - 2097152];
  else if (i < 6291456) v = s3[i - 4194304];
  else                  v = s4[i - 6291456];
  dst[i] = f2bf(v);
}

// ---- embedding + positional encoding: block per spatial pos, loop batch ----
__global__ __launch_bounds__(256)
void embed_kernel(const int* __restrict__ grd, const float* __restrict__ gold,
                  const float* __restrict__ emb, u16* __restrict__ xbf) {
  int p = blockIdx.x, c = threadIdx.x;           // p = y*64+x
  int y = p >> 6, xw = p & 63;
  int j = c & 63;
  float dv = expf(-(float)(2 * j) * (9.210340371976184f / 128.0f));
  float arg = ((c < 128) ? (float)xw : (float)y) * dv;
  float pos = (c & 64) ? cosf(arg) : sinf(arg);
  for (int b = 0; b < 16; ++b) {
    int t = b * 4096 + p;
    int g = grd[t];
    float v = (c < 254) ? emb[g * 254 + c] : gold[b * 2 + (c - 254)];
    xbf[(long)t * 256 + c] = f2bf(v + pos);
  }
}

// ============ gemm_qn: A staged ONCE, loop over all N tiles ============
template<int RELU, int ROWS>
__global__ __launch_bounds__(256)
void gemm_qn(const u16* __restrict__ A, const u16* __restrict__ W,
             const float* __restrict__ bias, u16* __restrict__ out,
             int Nout, int NT) {
  constexpr int NI = ROWS / 32;
  __shared__ u16 sA[ROWS * 256];
  __shared__ u16 sW[128 * 64];
  int tid = threadIdx.x;
  int lane = tid & 63, wave = tid >> 6;
  int wr = wave >> 1, wc = wave & 1;
  long rowbase = (long)blockIdx.x * ROWS;
  unsigned lbase = (unsigned)(tid & ~63) * 16;

  {
    int ac = tid & 31;
#pragma unroll
    for (int p = 0; p < ROWS / 8; ++p) {
      int row = p * 8 + (tid >> 5);
      int sc = (ac & 24) | ((ac ^ row) & 7);
      const u16* src = A + (rowbase + row) * 256 + sc * 8;
      __builtin_amdgcn_global_load_lds(
          (const __attribute__((address_space(1))) void*)src,
          (__attribute__((address_space(3))) void*)((char*)sA + p * 4096 + lbase),
          16, 0, 0);
    }
  }

  f32x4 acc[NI][4] = {};
  int T = NT * 4;
  for (int t = 0; t < T; ++t) {
    int nt = t >> 2, kc = t & 3;
    __syncthreads();
#pragma unroll
    for (int p = 0; p < 4; ++p) {
      int row = p * 32 + (tid >> 3);
      int sc = ((tid & 7) ^ row) & 7;
      const u16* src = W + (long)(nt * 128 + row) * 256 + kc * 64 + sc * 8;
      __builtin_amdgcn_global_load_lds(
          (const __attribute__((address_space(1))) void*)src,
          (__attribute__((address_space(3))) void*)((char*)sW + p * 4096 + lbase),
          16, 0, 0);
    }
    __syncthreads();

#pragma unroll
    for (int kk = 0; kk < 2; ++kk) {
      bf16x8 af[NI], bw[4];
#pragma unroll
      for (int i = 0; i < NI; ++i) {
        int ra = wr * (ROWS / 2) + i * 16 + (lane & 15);
        int l = kc * 8 + kk * 4 + (lane >> 4);
        int phys = (l & 24) | ((l ^ ra) & 7);
        af[i] = *(const bf16x8*)((const char*)sA + ra * 512 + phys * 16);
      }
#pragma unroll
      for (int j = 0; j < 4; ++j) {
        int rb = wc * 64 + j * 16 + (lane & 15);
        int m = kk * 4 + (lane >> 4);
        int phys = (m ^ rb) & 7;
        bw[j] = *(const bf16x8*)((const char*)sW + rb * 128 + phys * 16);
      }
#pragma unroll
      for (int i = 0; i < NI; ++i)
#pragma unroll
        for (int j = 0; j < 4; ++j)
          acc[i][j] = __builtin_amdgcn_mfma_f32_16x16x32_bf16(af[i], bw[j], acc[i][j], 0, 0, 0);
    }

    if (kc == 3) {
#pragma unroll
      for (int i = 0; i < NI; ++i) {
        long r0 = rowbase + wr * (ROWS / 2) + i * 16 + ((lane >> 4) * 4);
#pragma unroll
        for (int j = 0; j < 4; ++j) {
          long col = (long)nt * 128 + wc * 64 + j * 16 + (lane & 15);
          float bv = bias[col];
#pragma unroll
          for (int r = 0; r < 4; ++r) {
            float v = acc[i][j][r] + bv;
            if (RELU) v = fmaxf(v, 0.0f);
            out[(r0 + r) * Nout + col] = f2bf(v);
            acc[i][j][r] = 0.0f;
          }
        }
      }
    }
  }
}

// ====== gemm_pol: pol1 GEMM (N=512, ReLU) + pol2 (3x512 dot) fused ======
__global__ __launch_bounds__(256)
void gemm_pol(const u16* __restrict__ A, const u16* __restrict__ W,
              const float* __restrict__ b1, const float* __restrict__ pw2,
              const float* __restrict__ pb2, float* __restrict__ out) {
  __shared__ u16 sA[64 * 256];     // 32 KB
  __shared__ u16 sW[128 * 64];     // 16 KB
  __shared__ float part[2][3][64]; // 1.5 KB
  int tid = threadIdx.x;
  int lane = tid & 63, wave = tid >> 6;
  int wr = wave >> 1, wc = wave & 1;
  long rowbase = (long)blockIdx.x * 64;
  unsigned lbase = (unsigned)(tid & ~63) * 16;

  for (int i = tid; i < 384; i += 256) ((float*)part)[i] = 0.0f;

  {
    int ac = tid & 31;
#pragma unroll
    for (int p = 0; p < 8; ++p) {
      int row = p * 8 + (tid >> 5);
      int sc = (ac & 24) | ((ac ^ row) & 7);
      const u16* src = A + (rowbase + row) * 256 + sc * 8;
      __builtin_amdgcn_global_load_lds(
          (const __attribute__((address_space(1))) void*)src,
          (__attribute__((address_space(3))) void*)((char*)sA + p * 4096 + lbase),
          16, 0, 0);
    }
  }

  f32x4 acc[2][4] = {};
  for (int t = 0; t < 16; ++t) {          // NT=4 tiles x 4 k-chunks
    int nt = t >> 2, kc = t & 3;
    __syncthreads();
#pragma unroll
    for (int p = 0; p < 4; ++p) {
      int row = p * 32 + (tid >> 3);
      int sc = ((tid & 7) ^ row) & 7;
      const u16* src = W + (long)(nt * 128 + row) * 256 + kc * 64 + sc * 8;
      __builtin_amdgcn_global_load_lds(
          (const __attribute__((address_space(1))) void*)src,
          (__attribute__((address_space(3))) void*)((char*)sW + p * 4096 + lbase),
          16, 0, 0);
    }
    __syncthreads();

#pragma unroll
    for (int kk = 0; kk < 2; ++kk) {
      bf16x8 af[2], bw[4];
#pragma unroll
      for (int i = 0; i < 2; ++i) {
        int ra = wr * 32 + i * 16 + (lane & 15);
        int l = kc * 8 + kk * 4 + (lane >> 4);
        int phys = (l & 24) | ((l ^ ra) & 7);
        af[i] = *(const bf16x8*)((const char*)sA + ra * 512 + phys * 16);
      }
#pragma unroll
      for (int j = 0; j < 4; ++j) {
        int rb = wc * 64 + j * 16 + (lane & 15);
        int m = kk * 4 + (lane >> 4);
        int phys = (m ^ rb) & 7;
        bw[j] = *(const bf16x8*)((const char*)sW + rb * 128 + phys * 16);
      }
#pragma unroll
      for (int i = 0; i < 2; ++i)
#pragma unroll
        for (int j = 0; j < 4; ++j)
          acc[i][j] = __builtin_amdgcn_mfma_f32_16x16x32_bf16(af[i], bw[j], acc[i][j], 0, 0, 0);
    }

    if (kc == 3) {  // epilogue: h = relu(acc+b1); accumulate pol2 partials
#pragma unroll
      for (int i = 0; i < 2; ++i) {
#pragma unroll
        for (int r = 0; r < 4; ++r) {
          float p0 = 0.f, p1 = 0.f, p2 = 0.f;
#pragma unroll
          for (int j = 0; j < 4; ++j) {
            int col = nt * 128 + wc * 64 + j * 16 + (lane & 15);
            float v = fmaxf(acc[i][j][r] + b1[col], 0.0f);
            p0 += v * pw2[col];
            p1 += v * pw2[512 + col];
            p2 += v * pw2[1024 + col];
            acc[i][j][r] = 0.0f;
          }
#pragma unroll
          for (int m = 1; m < 16; m <<= 1) {
            p0 += __shfl_xor(p0, m); p1 += __shfl_xor(p1, m); p2 += __shfl_xor(p2, m);
          }
          if ((lane & 15) == 0) {
            int row = wr * 32 + i * 16 + (lane >> 4) * 4 + r;
            part[wc][0][row] += p0;
            part[wc][1][row] += p1;
            part[wc][2][row] += p2;
          }
        }
      }
    }
  }

  __syncthreads();
  if (tid < 64) {
    long t = rowbase + tid;
    float a0 = part[0][0][tid] + part[1][0][tid];
    float a1 = part[0][1][tid] + part[1][1][tid];
    float a2 = part[0][2][tid] + part[1][2][tid];
    out[t]          = a2 + pb2[2];
    out[65536 + t]  = a0 + pb2[0];
    out[131072 + t] = a1 + pb2[1];
  }
}

// ====== gemm_rln: GEMM(N=256) + bias + bf16 residual + LayerNorm fused ======
// 64 rows/block, 256 threads, 40KB LDS -> 4 blocks/CU. FINAL=1 additionally
// applies the network-final LayerNorm (g2,b2) in-register (layer 7 only):
// second stats round reuses red[] — pass-2 partials (red[0..511]) are disjoint
// from pass-1 stats (red[512..]); stats2 overwrite happens after a barrier.
template<int KC, int FINAL>
__global__ __launch_bounds__(256)
void gemm_rln(const u16* __restrict__ A, int lda, const u16* __restrict__ W,
              const float* __restrict__ bias, u16* __restrict__ xbf,
              const float* __restrict__ g, const float* __restrict__ b,
              const float* __restrict__ g2, const float* __restrict__ b2) {
  __shared__ __align__(16) char smem[40960];  // sA 8K | sW 32K; red overlays sA
  u16* sAr = (u16*)smem;
  u16* sWr = (u16*)(smem + 8192);
  float* red = (float*)smem;
  int tid = threadIdx.x;
  int lane = tid & 63, wave = tid >> 6;
  long rowbase = (long)blockIdx.x * 64;
  unsigned lbase = (unsigned)(tid & ~63) * 16;

  f32x4 acc[4][4] = {};
  for (int kc = 0; kc < KC; ++kc) {
    __syncthreads();
#pragma unroll
    for (int p = 0; p < 2; ++p) {
      int row = p * 32 + (tid >> 3);
      int sc = ((tid & 7) ^ row) & 7;
      const u16* src = A + (rowbase + row) * lda + kc * 64 + sc * 8;
      __builtin_amdgcn_global_load_lds(
          (const __attribute__((address_space(1))) void*)src,
          (__attribute__((address_space(3))) void*)((char*)sAr + p * 4096 + lbase),
          16, 0, 0);
    }
#pragma unroll
    for (int p = 0; p < 8; ++p) {
      int row = p * 32 + (tid >> 3);
      int sc = ((tid & 7) ^ row) & 7;
      const u16* src = W + (long)row * (KC * 64) + kc * 64 + sc * 8;
      __builtin_amdgcn_global_load_lds(
          (const __attribute__((address_space(1))) void*)src,
          (__attribute__((address_space(3))) void*)((char*)sWr + p * 4096 + lbase),
          16, 0, 0);
    }
    __syncthreads();

#pragma unroll
    for (int kk = 0; kk < 2; ++kk) {
      bf16x8 af[4], bw[4];
#pragma unroll
      for (int i = 0; i < 4; ++i) {
        int ra = i * 16 + (lane & 15);
        int m = kk * 4 + (lane >> 4);
        int phys = (m ^ ra) & 7;
        af[i] = *(const bf16x8*)((const char*)sAr + ra * 128 + phys * 16);
      }
#pragma unroll
      for (int j = 0; j < 4; ++j) {
        int rb = wave * 64 + j * 16 + (lane & 15);
        int m = kk * 4 + (lane >> 4);
        int phys = (m ^ rb) & 7;
        bw[j] = *(const bf16x8*)((const char*)sWr + rb * 128 + phys * 16);
      }
#pragma unroll
      for (int i = 0; i < 4; ++i)
#pragma unroll
        for (int j = 0; j < 4; ++j)
          acc[i][j] = __builtin_amdgcn_mfma_f32_16x16x32_bf16(af[i], bw[j], acc[i][j], 0, 0, 0);
    }
  }

  float gcol[4], bcol[4];
  long colb = wave * 64 + (lane & 15);
#pragma unroll
  for (int j = 0; j < 4; ++j) { gcol[j] = g[colb + j * 16]; bcol[j] = b[colb + j * 16]; }

  __syncthreads();

#pragma unroll
  for (int i = 0; i < 4; ++i) {
#pragma unroll
    for (int r = 0; r < 4; ++r) {
      int rowl = i * 16 + (lane >> 4) * 4 + r;
      long rbase = (rowbase + rowl) * 256;
      float ps = 0.f, pss = 0.f;
#pragma unroll
      for (int j = 0; j < 4; ++j) {
        float v = acc[i][j][r] + bias[colb + j * 16] + bf2f(xbf[rbase + colb + j * 16]);
        acc[i][j][r] = v;
        ps += v; pss += v * v;
      }
#pragma unroll
      for (int m = 1; m < 16; m <<= 1) { ps += __shfl_xor(ps, m); pss += __shfl_xor(pss, m); }
      if ((lane & 15) == 0) {
        red[wave * 64 + rowl] = ps;
        red[256 + wave * 64 + rowl] = pss;
      }
    }
  }
  __syncthreads();
  if (tid < 64) {
    float s = red[tid] + red[64 + tid] + red[128 + tid] + red[192 + tid];
    float ss = red[256 + tid] + red[320 + tid] + red[384 + tid] + red[448 + tid];
    float mean = s * (1.0f / 256.0f);
    float var = ss * (1.0f / 256.0f) - mean * mean;
    red[512 + tid * 2] = mean;
    red[512 + tid * 2 + 1] = rsqrtf(var + 1e-5f);
  }
  __syncthreads();

#pragma unroll
  for (int i = 0; i < 4; ++i) {
#pragma unroll
    for (int r = 0; r < 4; ++r) {
      int rowl = i * 16 + (lane >> 4) * 4 + r;
      float mean = red[512 + rowl * 2];
      float rstd = red[512 + rowl * 2 + 1];
      long rbase = (rowbase + rowl) * 256;
      float ps = 0.f, pss = 0.f;
#pragma unroll
      for (int j = 0; j < 4; ++j) {
        float o = (acc[i][j][r] - mean) * rstd * gcol[j] + bcol[j];
        if (FINAL) {
          acc[i][j][r] = o;          // keep LN2 output in f32 for pass 2
          ps += o; pss += o * o;
        } else {
          xbf[rbase + colb + j * 16] = f2bf(o);
        }
      }
      if (FINAL) {
#pragma unroll
        for (int m = 1; m < 16; m <<= 1) { ps += __shfl_xor(ps, m); pss += __shfl_xor(pss, m); }
        if ((lane & 15) == 0) {       // red[0..511]; red[512..] still read-only above
          red[wave * 64 + rowl] = ps;
          red[256 + wave * 64 + rowl] = pss;
        }
      }
    }
  }

  if (FINAL) {
    __syncthreads();
    if (tid < 64) {
      float s = red[tid] + red[64 + tid] + red[128 + tid] + red[192 + tid];
      float ss = red[256 + tid] + red[320 + tid] + red[384 + tid] + red[448 + tid];
      float mean = s * (1.0f / 256.0f);
      float var = ss * (1.0f / 256.0f) - mean * mean;
      red[512 + tid * 2] = mean;
      red[512 + tid * 2 + 1] = rsqrtf(var + 1e-5f);
    }
    __syncthreads();
    float g2col[4], b2col[4];
#pragma unroll
    for (int j = 0; j < 4; ++j) { g2col[j] = g2[colb + j * 16]; b2col[j] = b2[colb + j * 16]; }
#pragma unroll
    for (int i = 0; i < 4; ++i) {
#pragma unroll
      for (int r = 0; r < 4; ++r) {
        int rowl = i * 16 + (lane >> 4) * 4 + r;
        float mean = red[512 + rowl * 2];
        float rstd = red[512 + rowl * 2 + 1];
        long rbase = (rowbase + rowl) * 256;
#pragma unroll
        for (int j = 0; j < 4; ++j) {
          float o2 = (acc[i][j][r] - mean) * rstd * g2col[j] + b2col[j];
          xbf[rbase + colb + j * 16] = f2bf(o2);
        }
      }
    }
  }
}

// ------- hex attention: lane per (token, head-HALF) — 16 channels/lane -------
__global__ __launch_bounds__(256)
void attn_kernel(u16* __restrict__ qkv, const float* __restrict__ bin) {
  const int drA[7] = {0, 0, 0, 1, -1, -1, 1};
  const int dqA[7] = {0, 1, -1, 0, 0, 1, -1};
  int bid = blockIdx.x;
  int bswz = (bid & 7) * 512 + (bid >> 3);   // XCD-chunked, bijective (4096 = 8*512)
  int gid = bswz * 256 + threadIdx.x;
  int t = gid >> 4;
  int sub = gid & 15;
  int hoff = sub * 16;
  int b = t >> 12, y = (t >> 6) & 63, xw = t & 63;
  long tbase = (long)t * 768 + hoff;

  long tn[7]; float okf[7];
#pragma unroll
  for (int n = 0; n < 7; ++n) {
    int yy = y + drA[n], xx = xw + dqA[n];
    bool ok = ((unsigned)yy < 64u) && ((unsigned)xx < 64u);
    int yc = yy < 0 ? 0 : (yy > 63 ? 63 : yy);
    int xc = xx < 0 ? 0 : (xx > 63 ? 63 : xx);
    tn[n] = ((long)(b * 4096 + yc * 64 + xc)) * 768 + hoff;
    okf[n] = ok ? 1.0f : 0.0f;
  }

  u16x8 qraw[2], kr[7][2];
  {
    const u16x8* qp = (const u16x8*)(qkv + tbase);
    qraw[0] = qp[0]; qraw[1] = qp[1];
  }
#pragma unroll
  for (int n = 0; n < 7; ++n) {
    const u16x8* kp = (const u16x8*)(qkv + tn[n] + 256);
    kr[n][0] = kp[0]; kr[n][1] = kp[1];
  }

  float q[16];
#pragma unroll
  for (int j = 0; j < 2; ++j)
#pragma unroll
    for (int e = 0; e < 8; ++e) q[j * 8 + e] = bf2f(qraw[j][e]);

  float skb = 0.f;
  {
    const float* kb = bin + 256 + hoff;
#pragma unroll
    for (int i = 0; i < 16; ++i) skb += q[i] * kb[i];
  }

  float s[7];
#pragma unroll
  for (int n = 0; n < 7; ++n) {
    float acc = 0.f;
#pragma unroll
    for (int j = 0; j < 2; ++j)
#pragma unroll
      for (int e = 0; e < 8; ++e) acc += q[j * 8 + e] * bf2f(kr[n][j][e]);
    float p = (okf[n] != 0.f) ? acc : skb;
    p += __shfl_xor(p, 1);
    s[n] = p * 0.17677669529663687f;
  }

  u16x8 vr[7][2];
#pragma unroll
  for (int n = 0; n < 7; ++n) {
    const u16x8* vp = (const u16x8*)(qkv + tn[n] + 512);
    vr[n][0] = vp[0]; vr[n][1] = vp[1];
  }

  float mx = s[0];
#pragma unroll
  for (int n = 1; n < 7; ++n) mx = fmaxf(mx, s[n]);
  float wsum = 0.0f;
#pragma unroll
  for (int n = 0; n < 7; ++n) { s[n] = expf(s[n] - mx); wsum += s[n]; }
  float inv = 1.0f / wsum;

  float o[16];
#pragma unroll
  for (int i = 0; i < 16; ++i) o[i] = 0.0f;
  float woob = 0.f;
#pragma unroll
  for (int n = 0; n < 7; ++n) {
    float wk = okf[n] * s[n];
    woob += s[n] - wk;
#pragma unroll
    for (int j = 0; j < 2; ++j)
#pragma unroll
      for (int e = 0; e < 8; ++e) o[j * 8 + e] += wk * bf2f(vr[n][j][e]);
  }
  {
    const float* vb = bin + 512 + hoff;
#pragma unroll
    for (int i = 0; i < 16; ++i) o[i] += woob * vb[i];
  }

  u16x8* op = (u16x8*)(qkv + tbase);
#pragma unroll
  for (int j = 0; j < 2; ++j) {
    u16x8 ov;
#pragma unroll
    for (int e = 0; e < 8; ++e) ov[e] = f2bf(o[j * 8 + e] * inv);
    op[j] = ov;
  }
}

// ---------------- spatial mean pooling stage 1 (reads bf16) ----------------
__global__ __launch_bounds__(256)
void pool1_kernel(const u16* __restrict__ xbf, float* __restrict__ part) {
  int bid = blockIdx.x, c = threadIdx.x;
  long base = (long)bid * 128 * 256;
  float s = 0.f;
  for (int p = 0; p < 128; ++p) s += bf2f(xbf[base + (long)p * 256 + c]);
  part[(long)bid * 256 + c] = s;
}

// ---------------- pool stage 2 + value head fused: one block per batch ----------------
__global__ __launch_bounds__(256)
void value_kernel(const float* __restrict__ part, const float* __restrict__ cw1,
                  const float* __restrict__ cb1, const float* __restrict__ cw2,
                  const float* __restrict__ cb2, float* __restrict__ out) {
  __shared__ float pooled[256];
  __shared__ float red[2];
  int b = blockIdx.x, c = threadIdx.x;
  float s = 0.f;
  for (int seg = 0; seg < 32; ++seg) s += part[((long)b * 32 + seg) * 256 + c];
  pooled[c] = s * (1.0f / 4096.0f);
  __syncthreads();
  if (c < 128) {
    float hj = cb1[c];
    const float* wr = cw1 + c * 256;
    for (int k = 0; k < 256; ++k) hj += pooled[k] * wr[k];
    hj = fmaxf(hj, 0.0f);
    float acc = hj * cw2[c];
#pragma unroll
    for (int m = 1; m < 64; m <<= 1) acc += __shfl_xor(acc, m);
    if ((c & 63) == 0) red[c >> 6] = acc;
  }
  __syncthreads();
  if (c == 0) out[196608 + b] = red[0] + red[1] + cb2[0];
}

extern "C" void kernel_launch(void* const* d_in, const int* in_sizes, int n_in,
                              void* d_out, int out_size, void* d_ws, size_t ws_size,
                              hipStream_t stream) {
  const int*   grd  = (const int*)d_in[0];
  const float* gold = (const float*)d_in[1];
  const float* emb  = (const float*)d_in[2];
  const float* in_w = (const float*)d_in[3];
  const float* in_b = (const float*)d_in[4];
  const float* out_w= (const float*)d_in[5];
  const float* out_b= (const float*)d_in[6];
  const float* l1_w = (const float*)d_in[7];
  const float* l1_b = (const float*)d_in[8];
  const float* l2_w = (const float*)d_in[9];
  const float* l2_b = (const float*)d_in[10];
  const float* n1_g = (const float*)d_in[11];
  const float* n1_b = (const float*)d_in[12];
  const float* n2_g = (const float*)d_in[13];
  const float* n2_b = (const float*)d_in[14];
  const float* fn_g = (const float*)d_in[15];
  const float* fn_b = (const float*)d_in[16];
  const float* pw1  = (const float*)d_in[17];
  const float* pb1  = (const float*)d_in[18];
  const float* pw2  = (const float*)d_in[19];
  const float* pb2  = (const float*)d_in[20];
  const float* cw1  = (const float*)d_in[21];
  const float* cb1  = (const float*)d_in[22];
  const float* cw2  = (const float*)d_in[23];
  const float* cb2  = (const float*)d_in[24];
  float* out = (float*)d_out;

  // ---- workspace layout: peak ~175 MB ----
  char* ws = (char*)d_ws;
  u16*   xbf    = (u16*)ws;                            //   0..32 MB  bf16 residual stream
  char*  region = ws + (32l << 20);                    //  32..160 MB shared
  u16*   qkv    = (u16*)region;                        //   qkv [N,768] bf16 (96 MB)
  u16*   hbuf   = (u16*)region;                        //   ffn hidden full [N,1024] (128 MB)
  u16*   wbf    = (u16*)(ws + (160l << 20));           // 160..172.3 MB bf16 weights
  float* part   = (float*)(ws + (173l << 20));         // 173 MB +512 KB

  u16* inw_bf  = wbf;
  u16* outw_bf = inw_bf + 1572864;
  u16* l1w_bf  = outw_bf + 524288;
  u16* l2w_bf  = l1w_bf + 2097152;
  u16* pw1_bf  = l2w_bf + 2097152;

  // all 5 weight conversions in one launch (wbf is contiguous in this order)
  cvt_all<<<25088, 256, 0, stream>>>(in_w, out_w, l1_w, l2_w, pw1, wbf);

  // embedding + posenc: block per spatial position, batch loop inside
  embed_kernel<<<4096, 256, 0, stream>>>(grd, gold, emb, xbf);

  for (int i = 0; i < 8; ++i) {
    // QKV projection: 128-row blocks (A staged once wins here), 6 N-tiles
    gemm_qn<0, 128><<<512, 256, 0, stream>>>(
        xbf, inw_bf + (long)i * 196608, in_b + i * 768, qkv, 768, 6);
    // hex attention, half-head per lane, in place into q-slice
    attn_kernel<<<4096, 256, 0, stream>>>(qkv, in_b + i * 768);
    // out-projection + bf16 residual + LN1
    gemm_rln<4, 0><<<1024, 256, 0, stream>>>(
        qkv, 768, outw_bf + (long)i * 65536, out_b + i * 256, xbf,
        n1_g + i * 256, n1_b + i * 256, n1_g + i * 256, n1_b + i * 256);
    // FFN over full N (hbuf 128 MB aliases dead qkv)
    gemm_qn<1, 128><<<512, 256, 0, stream>>>(
        xbf, l1w_bf + (long)i * 262144, l1_b + i * 1024, hbuf, 1024, 8);
    if (i < 7) {
      gemm_rln<16, 0><<<1024, 256, 0, stream>>>(
          hbuf, 1024, l2w_bf + (long)i * 262144, l2_b + i * 256, xbf,
          n2_g + i * 256, n2_b + i * 256, n2_g + i * 256, n2_b + i * 256);
    } else {
      // layer 7: fuse the network-final LayerNorm into the LN2 epilogue
      gemm_rln<16, 1><<<1024, 256, 0, stream>>>(
          hbuf, 1024, l2w_bf + (long)i * 262144, l2_b + i * 256, xbf,
          n2_g + i * 256, n2_b + i * 256, fn_g, fn_b);
    }
  }

  // policy head: pol1 GEMM + pol2 fused, no hidden materialization
  gemm_pol<<<1024, 256, 0, stream>>>(xbf, pw1_bf, pb1, pw2, pb2, out);

  // value head: pool1 then fused pool2+value
  pool1_kernel<<<512, 256, 0, stream>>>(xbf, part);
  value_kernel<<<16, 256, 0, stream>>>(part, cw1, cb1, cw2, cb2, out);
}